// Round 12
// baseline (234.485 us; speedup 1.0000x reference)
//
#include <hip/hip_runtime.h>
#include <math.h>

typedef unsigned short u16;
typedef unsigned int   u32;
typedef unsigned long long u64;

#define NATOMS 8192
#define GRAPHS 64
#define KNN    32
#define NGAUSS 50
#define HID    128
#define LAYERS 6
#define NTAB   4096
#define SA     136   // u16 stride, 272B rows (16B-aligned, 4-bank row shift)
#define SW1    72    // u16 stride for staged mw1 rows
#define SH     132   // f32 stride for head h staging

typedef __attribute__((ext_vector_type(8))) short bf16x8;
typedef __attribute__((ext_vector_type(4))) float f32x4;

__device__ __forceinline__ float bf2f(u16 v) {
    return __uint_as_float(((u32)v) << 16);
}
__device__ __forceinline__ u16 f2bf(float f) {
    u32 u = __float_as_uint(f);
    u32 lsb = (u >> 16) & 1u;
    u += 0x7fffu + lsb;
    return (u16)(u >> 16);
}
__device__ __forceinline__ u32 pkbf(float lo, float hi) {
#if __has_builtin(__builtin_amdgcn_cvt_pk_bf16_f32)
    auto r = __builtin_amdgcn_cvt_pk_bf16_f32(lo, hi);
    u32 u; __builtin_memcpy(&u, &r, 4); return u;
#else
    return (u32)f2bf(lo) | ((u32)f2bf(hi) << 16);
#endif
}
__device__ __forceinline__ float silu_f(float x) {
    return x * __builtin_amdgcn_rcpf(1.0f + __expf(-x));
}
__device__ __forceinline__ bf16x8 ldfrag(const u16* p) {
    return *(const bf16x8*)__builtin_assume_aligned(p, 16);
}
__device__ __forceinline__ u64 shfl_xor_u64(u64 v, int mask) {
    u32 lo = (u32)v, hi = (u32)(v >> 32);
    lo = (u32)__shfl_xor((int)lo, mask, 64);
    hi = (u32)__shfl_xor((int)hi, mask, 64);
    return ((u64)hi << 32) | lo;
}
__device__ __forceinline__ float ldf(const void* p, int i, bool f32in) {
    return f32in ? ((const float*)p)[i] : bf2f(((const u16*)p)[i]);
}
union U8 { bf16x8 v; u32 w[4]; };

// ---------------------------------------------------------------------------
// K0: dtype probe + zero rev_cnt/gsum/done/exchange-flags.
// ---------------------------------------------------------------------------
__global__ void probe_kernel(const u16* __restrict__ raw, int* __restrict__ flag,
                             int* __restrict__ rev_cnt, float* __restrict__ gsum,
                             int* __restrict__ done_cnt, int* __restrict__ xflags) {
    __shared__ int s;
    int t = threadIdx.x;
    if (t == 0) s = 0;
    __syncthreads();
    float x = bf2f(raw[2 * t]);
    if (!(fabsf(x) < 1000.0f)) atomicOr(&s, 1);
    for (int i = t; i < NATOMS; i += 256) rev_cnt[i] = 0;
    for (int i = t; i < 2048; i += 256) xflags[i] = 0;
    if (t < GRAPHS) gsum[t] = 0.0f;
    if (t == 0) *done_cnt = 0;
    __syncthreads();
    if (t == 0) *flag = s;
}

// ---------------------------------------------------------------------------
// K1: merged setup — build_graph + weight prep (l1wt/l2wt only) + fp32 ingest.
// rev entries packed: (table_row << 7) | local_sender  (12b + 7b).
// ---------------------------------------------------------------------------
#define NARR 9
struct IngestDesc {
    const void* src[NARR];
    void*       dst[NARR];
    int         n[NARR];
};

#define NB_BUILD 2048
#define NB_PREP  768

__launch_bounds__(256)
__global__ void setup_kernel(const void* __restrict__ pos,
                             const void* __restrict__ l1w, const void* __restrict__ l2w,
                             u16* __restrict__ l1wt, u16* __restrict__ l2wt,
                             IngestDesc d, int total_ing,
                             const int* __restrict__ flag,
                             int* __restrict__ rev_cnt, u32* __restrict__ rev) {
    int bid = blockIdx.x;
    bool f32in = (*flag != 0);
    if (bid < NB_BUILD) {
        int wv = threadIdx.x >> 6, lane = threadIdx.x & 63;
        int t = bid * 4 + wv;
        int tl = t & 127;
        int base = t & ~127;
        float cx = ldf(pos, t * 3 + 0, f32in);
        float cy = ldf(pos, t * 3 + 1, f32in);
        float cz = ldf(pos, t * 3 + 2, f32in);
        u64 key[2];
#pragma unroll
        for (int c = 0; c < 2; ++c) {
            int j = lane + c * 64;
            float jx = ldf(pos, (base + j) * 3 + 0, f32in);
            float jy = ldf(pos, (base + j) * 3 + 1, f32in);
            float jz = ldf(pos, (base + j) * 3 + 2, f32in);
            float dx = __fsub_rn(cx, jx);
            float dy = __fsub_rn(cy, jy);
            float dz = __fsub_rn(cz, jz);
            float d2 = __fadd_rn(__fadd_rn(__fmul_rn(dx, dx), __fmul_rn(dy, dy)),
                                 __fmul_rn(dz, dz));
            bool valid = (j != tl) && (d2 < 100.0f);
            key[c] = valid ? ((((u64)__float_as_uint(d2)) << 32) | (u32)j) : ~0ULL;
        }
#pragma unroll
        for (int k = 2; k <= 128; k <<= 1) {
#pragma unroll
            for (int j = k >> 1; j > 0; j >>= 1) {
                if (j == 64) {
                    u64 lo = key[0] < key[1] ? key[0] : key[1];
                    u64 hi = key[0] < key[1] ? key[1] : key[0];
                    key[0] = lo; key[1] = hi;
                } else {
#pragma unroll
                    for (int r = 0; r < 2; ++r) {
                        u64 o = shfl_xor_u64(key[r], j);
                        u32 ii = (u32)(r * 64 + lane);
                        bool dir = ((ii & (u32)k) == 0);
                        bool lower = ((ii & (u32)j) == 0);
                        bool keep_min = (dir == lower);
                        bool less = key[r] < o;
                        key[r] = (less == keep_min) ? key[r] : o;
                    }
                }
            }
        }
        if (lane < KNN) {
            u64 m = key[0];
            if (m != ~0ULL) {
                float d2 = __uint_as_float((u32)(m >> 32));
                float dd = __fsqrt_rn(d2);
                if (dd < 10.0f) {
                    float u = dd * ((float)(NTAB - 1) / 10.0f);
                    int i0 = (int)(u + 0.5f);          // nearest
                    if (i0 > NTAB - 1) i0 = NTAB - 1;
                    int jn = base + (int)(m & 0xffffffffu);
                    int p = atomicAdd(&rev_cnt[jn], 1);
                    rev[(size_t)jn * 128 + p] = ((u32)i0 << 7) | (u32)(t & 127);
                }
            }
        }
    } else if (bid < NB_BUILD + NB_PREP) {
        int gid = (bid - NB_BUILD) * 256 + threadIdx.x;
        int seg = gid / 98304;
        int tt = gid % 98304;
        int l = tt >> 14;
        int n = (tt >> 7) & 127;
        int k = tt & 127;
        const void* src = (seg == 0) ? l1w : l2w;
        u16* dst = (seg == 0) ? l1wt : l2wt;
        int si = l * 16384 + k * 128 + n;
        float v = f32in ? ((const float*)src)[si] : bf2f(((const u16*)src)[si]);
        dst[tt] = f2bf(v);
    } else {
        int gid = (bid - NB_BUILD - NB_PREP) * 256 + threadIdx.x;
        if (gid < total_ing) {
            int a = 0, off = gid;
            while (off >= d.n[a]) { off -= d.n[a]; ++a; }
            float v = f32in ? ((const float*)d.src[a])[off]
                            : bf2f(((const u16*)d.src[a])[off]);
            ((float*)d.dst[a])[off] = v;
        }
    }
}

// ---------------------------------------------------------------------------
// K4a: filter tables via MFMA. Stages mw1/mw2 straight from the RAW inputs
// with inline transpose + dtype convert.
// ---------------------------------------------------------------------------
__launch_bounds__(256)
__global__ void vtab_kernel(const void* __restrict__ mw1,   // raw [6][50][128]
                            const void* __restrict__ mw2,   // raw [6][128][128]
                            const float* __restrict__ b1,   // [6][128] canonical
                            const float* __restrict__ b2,   // [6][128]
                            const int* __restrict__ flag,
                            u32* __restrict__ pk) {         // [6][NTAB][64]
    __shared__ u16 s_t1[128 * SA];
    __shared__ u16 s_w1[128 * SW1];
    __shared__ u16 s_w2[128 * SA];
    int tid = threadIdx.x;
    int l = blockIdx.x / (NTAB / 128);
    int rbase = (blockIdx.x % (NTAB / 128)) * 128;
    {
        bool f32in = (*flag != 0);
#pragma unroll
        for (int p = 0; p < 32; ++p) {
            int idx = p * 256 + tid;           // 8192 = 128n x 64k
            int k = idx >> 7, n = idx & 127;
            float v = (k < 50) ? ldf(mw1, l * 6400 + k * 128 + n, f32in) : 0.0f;
            s_w1[n * SW1 + k] = f2bf(v);
        }
#pragma unroll
        for (int p = 0; p < 64; ++p) {
            int idx = p * 256 + tid;           // 16384 = 128n x 128k
            int k = idx >> 7, n = idx & 127;
            s_w2[n * SA + k] = f2bf(ldf(mw2, l * 16384 + k * 128 + n, f32in));
        }
    }
    __syncthreads();

    int wv = tid >> 6, lane = tid & 63;
    int quad = lane >> 4, lr = lane & 15;
    int m0 = wv * 32;

    {
        const float wgi = 49.0f / 10.0f;
        const float dstep = 10.0f / (float)(NTAB - 1);
        U8 afr[2][2];
#pragma unroll
        for (int mt = 0; mt < 2; ++mt) {
            float d = (float)(rbase + m0 + mt * 16 + lr) * dstep;
            float u = d * wgi;
#pragma unroll
            for (int kki = 0; kki < 2; ++kki) {
                float t0 = u - (float)(quad * 8) - (float)(kki * 32);
                float vj[8];
#pragma unroll
                for (int j = 0; j < 8; ++j) {
                    float tt = t0 - (float)j;
                    float e = __expf(-0.5f * tt * tt);
                    if (kki == 1 && (quad * 8 + j) >= 18) e = 0.0f;
                    vj[j] = e;
                }
#pragma unroll
                for (int p = 0; p < 4; ++p)
                    afr[mt][kki].w[p] = pkbf(vj[2 * p], vj[2 * p + 1]);
            }
        }
        f32x4 accA[2][8];
#pragma unroll
        for (int mt = 0; mt < 2; ++mt)
#pragma unroll
            for (int nt = 0; nt < 8; ++nt) accA[mt][nt] = (f32x4){0.f, 0.f, 0.f, 0.f};
#pragma unroll
        for (int kki = 0; kki < 2; ++kki) {
#pragma unroll
            for (int nt = 0; nt < 8; ++nt) {
                bf16x8 b = ldfrag(&s_w1[(nt * 16 + lr) * SW1 + kki * 32 + quad * 8]);
                accA[0][nt] = __builtin_amdgcn_mfma_f32_16x16x32_bf16(afr[0][kki].v, b, accA[0][nt], 0, 0, 0);
                accA[1][nt] = __builtin_amdgcn_mfma_f32_16x16x32_bf16(afr[1][kki].v, b, accA[1][nt], 0, 0, 0);
            }
        }
#pragma unroll
        for (int mt = 0; mt < 2; ++mt) {
            int r0 = m0 + mt * 16 + quad * 4;
            u16* tp0 = &s_t1[r0 * SA + lr];
#pragma unroll
            for (int nt = 0; nt < 8; ++nt) {
                int col = nt * 16;
                float bb = b1[l * 128 + col + lr];
                u32 p01 = pkbf(silu_f(accA[mt][nt][0] + bb),
                               silu_f(accA[mt][nt][1] + bb));
                u32 p23 = pkbf(silu_f(accA[mt][nt][2] + bb),
                               silu_f(accA[mt][nt][3] + bb));
                u16* tp = tp0 + col;
                tp[0]      = (u16)p01;
                tp[SA]     = (u16)(p01 >> 16);
                tp[2 * SA] = (u16)p23;
                tp[3 * SA] = (u16)(p23 >> 16);
            }
        }
    }
    // no barrier: Phase B reads only this wave's own 32 t1 rows
    {
        f32x4 accB[2][8];
#pragma unroll
        for (int mt = 0; mt < 2; ++mt)
#pragma unroll
            for (int nt = 0; nt < 8; ++nt) accB[mt][nt] = (f32x4){0.f, 0.f, 0.f, 0.f};
#pragma unroll
        for (int kk = 0; kk < 128; kk += 32) {
            bf16x8 a0 = ldfrag(&s_t1[(m0 + lr)      * SA + kk + quad * 8]);
            bf16x8 a1 = ldfrag(&s_t1[(m0 + 16 + lr) * SA + kk + quad * 8]);
#pragma unroll
            for (int nt = 0; nt < 8; ++nt) {
                bf16x8 b = ldfrag(&s_w2[(nt * 16 + lr) * SA + kk + quad * 8]);
                accB[0][nt] = __builtin_amdgcn_mfma_f32_16x16x32_bf16(a0, b, accB[0][nt], 0, 0, 0);
                accB[1][nt] = __builtin_amdgcn_mfma_f32_16x16x32_bf16(a1, b, accB[1][nt], 0, 0, 0);
            }
        }
        const float dstep = 10.0f / (float)(NTAB - 1);
#pragma unroll
        for (int mt = 0; mt < 2; ++mt) {
            int r0 = m0 + mt * 16 + quad * 4;
            float cv[4];
#pragma unroll
            for (int r = 0; r < 4; ++r) {
                float d = (float)(rbase + r0 + r) * dstep;
                cv[r] = 0.5f * (cosf(d * 3.14159265f / 10.0f) + 1.0f);
            }
#pragma unroll
            for (int nt = 0; nt < 8; ++nt) {
                int col = nt * 16 + lr;
                float bb = b2[l * 128 + col];
#pragma unroll
                for (int r = 0; r < 4; ++r) {
                    float val = (accB[mt][nt][r] + bb) * cv[r];
                    float oth = __shfl_xor(val, 1, 64);
                    if ((lr & 1) == 0) {
                        int row = rbase + r0 + r;
                        pk[((size_t)l * NTAB + row) * 64 + (col >> 1)] =
                            pkbf(val, oth);
                    }
                }
            }
        }
    }
}

// ---------------------------------------------------------------------------
// K5: graph kernel — FOUR BLOCKS PER GRAPH (256 blocks x 1024 thr = all CUs).
// r12 vs r11: pipelined wave-partitioned exchange pull. Waves statically map
// to partners (w%3); each wave's lane-0 spins on ITS partner flag then the
// wave immediately pulls its strided share — early partners' data streams in
// while late flags are awaited (r11 serialized the full 24KB pull behind the
// slowest flag). asm memory clobber pins compiler order; HW issues data loads
// after the observed flag (in-order vmem issue). Final syncthreads preserves
// the r11 parity-race proof. 5 barriers/layer (was 6). Math untouched.
// ---------------------------------------------------------------------------
#define AGG_ISSUE(T, X, base, ev)                                              \
    {                                                                          \
        _Pragma("unroll") for (int q = 0; q < 8; ++q) {                        \
            int e = (base) + q;                                                \
            u32 pe = __builtin_amdgcn_readlane((ev), e & 63);                  \
            int sy = (int)(pe >> 7);                                           \
            int sx = (int)(pe & 127u);                                         \
            T[q] = pkl[(size_t)sy * 64 + lane];                                \
            X[q] = *(const u32*)&s_x[sx * SA + c2];                            \
        }                                                                      \
    }

#define AGG_COMPUTE(T, X)                                                      \
    {                                                                          \
        _Pragma("unroll") for (int q = 0; q < 8; ++q) {                        \
            float v0 = bf2f((u16)T[q]) * bf2f((u16)X[q]);                      \
            float v1 = bf2f((u16)(T[q] >> 16)) * bf2f((u16)(X[q] >> 16));      \
            switch (q & 3) {                                                   \
                case 0: a0 += v0; a1 += v1; break;                             \
                case 1: b0 += v0; b1v += v1; break;                            \
                case 2: c0 += v0; c1 += v1; break;                             \
                default: d0 += v0; d1 += v1; break;                            \
            }                                                                  \
        }                                                                      \
    }

__launch_bounds__(1024, 1)
__global__ void graph_kernel(const int* __restrict__ rev_cnt,
                             const u32* __restrict__ rev,
                             const u32* __restrict__ pk,      // [6][NTAB][64]
                             const int* __restrict__ z,
                             const float* __restrict__ emb,
                             const u16* __restrict__ l1wt,
                             const float* __restrict__ l1b,
                             const u16* __restrict__ l2wt,
                             const float* __restrict__ l2b,
                             const float* __restrict__ ow1,
                             const float* __restrict__ ob1,
                             const float* __restrict__ ow2,
                             const float* __restrict__ ob2,
                             u32* __restrict__ xbuf,          // [256][2][2048]
                             int* __restrict__ xflags,        // [64][4][8]
                             float* __restrict__ gsum,
                             int* __restrict__ done_cnt,
                             void* __restrict__ out,
                             const int* __restrict__ flag) {
    __shared__ __align__(16) u16 s_x[128 * SA];      // full xj (head: ow1 f32)
    __shared__ __align__(16) u16 s_hb[64 * SA];      // own h bf16 (32 used; pad)
    __shared__ __align__(16) u16 s_pair[2 * 64 * SA];// agg hi|lo (head: h f32)
    __shared__ float s_b1a[LAYERS * 128];            // all-layer biases
    __shared__ float s_b2a[LAYERS * 128];
    __shared__ int s_gp[4][32];                      // serpentine loc->glob row
    __shared__ float s_sum;
    __shared__ int s_last;

    u16* s_ahi = s_pair;
    u16* s_alo = s_pair + 64 * SA;

    int tid = threadIdx.x;
    int bid = blockIdx.x;
    int g = bid & 63, q4 = bid >> 6;        // quarter 0..3
    int abase = g * 128;
    int w = tid >> 6, lane = tid & 63;
    int quad = lane >> 4, lr = lane & 15;
    int rowt = (w >> 3) * 16;               // compact row tile (0 or 16)
    int coln = (w & 7) * 16;                // col tile base (0..112)
    int c2 = lane * 2;

    float hreg[4];                          // h[rowt+quad*4+r][coln+lr] compact

    // ---- hoisted: all-layer biases -> LDS (written once, covered by sync)
    for (int i = tid; i < LAYERS * 128; i += 1024) {
        s_b1a[i] = l1b[i];
        s_b2a[i] = l2b[i];
    }

    // ---- wave 0: sort ALL 128 receiver degrees desc (2 keys/lane bitonic,
    //      deterministic & identical in all 4 partner blocks), then assign
    //      serpentine: position p -> round r=p>>2, col c=p&3, block
    //      q=(r&1)?3-c:c. Block totals equalize.
    if (w == 0) {
        u32 key[2];
#pragma unroll
        for (int c = 0; c < 2; ++c) {
            int rowi = lane + c * 64;
            int dg = rev_cnt[abase + rowi];
            key[c] = ((u32)dg << 8) | (u32)rowi;
        }
#pragma unroll
        for (int k = 2; k <= 128; k <<= 1) {
#pragma unroll
            for (int j = k >> 1; j > 0; j >>= 1) {
                if (j == 64) {
                    u32 mx = key[0] > key[1] ? key[0] : key[1];
                    u32 mn = key[0] > key[1] ? key[1] : key[0];
                    key[0] = mx; key[1] = mn;
                } else {
#pragma unroll
                    for (int r = 0; r < 2; ++r) {
                        u32 o = (u32)__shfl_xor((int)key[r], j, 64);
                        u32 ii = (u32)(r * 64 + lane);
                        bool dir = ((ii & (u32)k) == 0);
                        bool lower = ((ii & (u32)j) == 0);
                        bool keep_max = (dir == lower);
                        bool greater = key[r] > o;
                        key[r] = (greater == keep_max) ? key[r] : o;
                    }
                }
            }
        }
#pragma unroll
        for (int c = 0; c < 2; ++c) {
            int p = lane + c * 64;
            int r = p >> 2, cc = p & 3;
            int q = (r & 1) ? (3 - cc) : cc;
            s_gp[q][r] = (int)(key[c] & 0xffu);
        }
    }
    __syncthreads();

    // ---- init: stage own 32 emb[z] rows (compact order) -> s_hb (bf16)
    {
        int r = tid >> 5, cb = (tid & 31) * 4;
        const float* src = emb + (size_t)z[abase + s_gp[q4][r]] * 128 + cb;
        float4 v = *(const float4*)src;
        u32* dd = (u32*)&s_hb[r * SA + cb];
        dd[0] = pkbf(v.x, v.y); dd[1] = pkbf(v.z, v.w);
    }

    // ---- hoisted: per-wave receiver descriptors (layer-invariant, balanced)
    int rloc[2];
    rloc[0] = w;
    rloc[1] = 31 - w;
    int grow[2];
    grow[0] = s_gp[q4][rloc[0]];
    grow[1] = s_gp[q4][rloc[1]];
    int dgv[2];
    u32 eAv[2], eBv[2];
#pragma unroll
    for (int rr = 0; rr < 2; ++rr) {
        int j = abase + grow[rr];
        dgv[rr] = rev_cnt[j];
        eAv[rr] = rev[(size_t)j * 128 + lane];
        eBv[rr] = (dgv[rr] > 64) ? rev[(size_t)j * 128 + 64 + lane] : eAv[rr];
    }
    __syncthreads();

    // ---- gemm0: own xj(0) rows -> s_x[glob rows]
    {
        f32x4 acc = (f32x4){0.f, 0.f, 0.f, 0.f};
#pragma unroll
        for (int kk = 0; kk < 128; kk += 32) {
            bf16x8 a = ldfrag(&s_hb[(rowt + lr) * SA + kk + quad * 8]);
            bf16x8 b = ldfrag(l1wt + (coln + lr) * 128 + kk + quad * 8);
            acc = __builtin_amdgcn_mfma_f32_16x16x32_bf16(a, b, acc, 0, 0, 0);
        }
#pragma unroll
        for (int r = 0; r < 4; ++r) {
            int col = coln + lr;
            s_x[s_gp[q4][rowt + quad * 4 + r] * SA + col] =
                f2bf(acc[r] + s_b1a[col]);
        }
    }

    for (int l = 0; l <= LAYERS; ++l) {
        if (l < LAYERS) {
            // ---- all-gather exchange e=l: own quarter out, pipelined pull
            int e = l;
            u64* xbw = (u64*)(xbuf + ((size_t)bid * 2 + (e & 1)) * 2048);
            __syncthreads();                    // s_x own writes visible
            {
                // 1024 u64 = 32 loc-rows x 32 (u64 covers 4 u16)
                u64 v = *(const u64*)&s_x[s_gp[q4][tid >> 5] * SA +
                                          (tid & 31) * 4];
                __hip_atomic_store(&xbw[tid], v, __ATOMIC_RELAXED,
                                   __HIP_MEMORY_SCOPE_SYSTEM);
            }
            __syncthreads();                    // vmcnt drained: data at IC
            if (tid == 0)
                __hip_atomic_store(&xflags[(g * 4 + q4) * 8 + e], 1,
                                   __ATOMIC_RELAXED, __HIP_MEMORY_SCOPE_SYSTEM);
            // wave-partitioned pipelined pull: wave w -> partner (w%3);
            // lane-0 spins on that partner's flag, then the wave pulls its
            // strided chunks. Early partners stream while late flags pend.
            {
                int k = w % 3;
                int pq = (q4 + 1 + k) & 3;
                int widx = w / 3;               // 0..5 (k=0), 0..4 (k=1,2)
                int gsz = (k == 0) ? 6 : 5;
                if (lane == 0) {
                    const int* pf = &xflags[(g * 4 + pq) * 8 + e];
                    while (__hip_atomic_load(pf, __ATOMIC_RELAXED,
                                             __HIP_MEMORY_SCOPE_SYSTEM) == 0)
                        __builtin_amdgcn_s_sleep(1);
                }
                asm volatile("" ::: "memory");  // pin loads after flag observe
                const u64* xbr = (const u64*)(xbuf +
                    ((size_t)(g + 64 * pq) * 2 + (e & 1)) * 2048);
                for (int c = widx; c < 16; c += gsz) {
                    int i = c * 64 + lane;
                    u64 v = __hip_atomic_load(&xbr[i], __ATOMIC_RELAXED,
                                              __HIP_MEMORY_SCOPE_SYSTEM);
                    *(u64*)&s_x[s_gp[pq][i >> 5] * SA + (i & 31) * 4] = v;
                }
            }
            __syncthreads();
        }
        if (l == LAYERS) break;

        const u32* pkl = pk + (size_t)l * NTAB * 64;

        // ---- Phase 1: agg — wave w owns compact receivers {w, 31-w}
#pragma unroll
        for (int rr = 0; rr < 2; ++rr) {
            int row = rloc[rr];                     // compact 0..31
            int deg = dgv[rr];
            u32 e0 = eAv[rr];
            u32 e1 = eBv[rr];
            float a0 = 0.f, a1 = 0.f, b0 = 0.f, b1v = 0.f;
            float c0 = 0.f, c1 = 0.f, d0 = 0.f, d1 = 0.f;
            u32 tA[8], xA[8], tB[8], xB[8];
            int ng = deg >> 3;
            if (ng > 0) {
                AGG_ISSUE(tA, xA, 0, e0);
                int gi = 1;
                for (; gi + 1 < ng; gi += 2) {
                    u32 evB = (gi < 8) ? e0 : e1;
                    AGG_ISSUE(tB, xB, gi * 8, evB);
                    AGG_COMPUTE(tA, xA);
                    u32 evA = ((gi + 1) < 8) ? e0 : e1;
                    AGG_ISSUE(tA, xA, (gi + 1) * 8, evA);
                    AGG_COMPUTE(tB, xB);
                }
                if (gi < ng) {
                    u32 evB = (gi < 8) ? e0 : e1;
                    AGG_ISSUE(tB, xB, gi * 8, evB);
                    AGG_COMPUTE(tA, xA);
                    AGG_COMPUTE(tB, xB);
                } else {
                    AGG_COMPUTE(tA, xA);
                }
            }
            for (int it = ng * 8; it < deg; ++it) {
                u32 ev = (it < 64) ? e0 : e1;
                u32 pe = __builtin_amdgcn_readlane(ev, it & 63);
                int sy = (int)(pe >> 7);
                int sx = (int)(pe & 127u);
                u32 t = pkl[(size_t)sy * 64 + lane];
                u32 x = *(const u32*)&s_x[sx * SA + c2];
                a0 += bf2f((u16)t) * bf2f((u16)x);
                a1 += bf2f((u16)(t >> 16)) * bf2f((u16)(x >> 16));
            }
            float sxv = (a0 + b0) + (c0 + d0);
            float syv = (a1 + b1v) + (c1 + d1);
            u32 hp = pkbf(sxv, syv);
            u32 lp = pkbf(sxv - bf2f((u16)hp), syv - bf2f((u16)(hp >> 16)));
            *(u32*)&s_ahi[row * SA + c2] = hp;
            *(u32*)&s_alo[row * SA + c2] = lp;
        }
        __syncthreads();

        // ---- Phase 2: h += silu(agg @ l2w + b2) [hi/lo A], h in VGPRs
        {
            const u16* B2t = l2wt + (size_t)l * 16384;
            f32x4 acc = (f32x4){0.f, 0.f, 0.f, 0.f};
#pragma unroll
            for (int kk = 0; kk < 128; kk += 32) {
                bf16x8 ah = ldfrag(&s_ahi[(rowt + lr) * SA + kk + quad * 8]);
                bf16x8 al = ldfrag(&s_alo[(rowt + lr) * SA + kk + quad * 8]);
                bf16x8 b = ldfrag(B2t + (coln + lr) * 128 + kk + quad * 8);
                acc = __builtin_amdgcn_mfma_f32_16x16x32_bf16(ah, b, acc, 0, 0, 0);
                acc = __builtin_amdgcn_mfma_f32_16x16x32_bf16(al, b, acc, 0, 0, 0);
            }
            if (l == LAYERS - 1 && tid == 0) s_sum = 0.0f;
            int col = coln + lr;
#pragma unroll
            for (int r = 0; r < 4; ++r) {
                int row = rowt + quad * 4 + r;          // compact
                float hold = (l == 0)
                    ? emb[(size_t)z[abase + s_gp[q4][row]] * 128 + col]
                    : hreg[r];
                float hn = hold + silu_f(acc[r] + s_b2a[l * 128 + col]);
                hreg[r] = hn;
                if (l < LAYERS - 1) s_hb[row * SA + col] = f2bf(hn);
            }
        }
        __syncthreads();

        if (l < LAYERS - 1) {
            // ---- Phase 3: own xj(l+1) rows -> s_x[glob rows]
            const u16* B1n = l1wt + (size_t)(l + 1) * 16384;
            f32x4 ac2 = (f32x4){0.f, 0.f, 0.f, 0.f};
#pragma unroll
            for (int kk = 0; kk < 128; kk += 32) {
                bf16x8 a = ldfrag(&s_hb[(rowt + lr) * SA + kk + quad * 8]);
                bf16x8 b = ldfrag(B1n + (coln + lr) * 128 + kk + quad * 8);
                ac2 = __builtin_amdgcn_mfma_f32_16x16x32_bf16(a, b, ac2, 0, 0, 0);
            }
            int col = coln + lr;
#pragma unroll
            for (int r = 0; r < 4; ++r) {
                s_x[s_gp[q4][rowt + quad * 4 + r] * SA + col] =
                    f2bf(ac2[r] + s_b1a[(l + 1) * 128 + col]);
            }
            // exchange at top of next iteration (e = l+1)
        } else {
            // ---- Last layer: head on own 32 atoms (compact) from hreg
            float* s_hf = (float*)s_pair;       // 32*SH*4 = 16.9KB
            float* s_w  = (float*)s_x;          // 32KB (ow1 [128][64])
            {
                float4* dst = (float4*)s_w;
                const float4* src4 = (const float4*)ow1;
                dst[tid] = src4[tid];
                dst[tid + 1024] = src4[tid + 1024];
            }
#pragma unroll
            for (int r = 0; r < 4; ++r)
                s_hf[(rowt + quad * 4 + r) * SH + coln + lr] = hreg[r];
            __syncthreads();
            int atom = tid >> 5, cg = tid & 31;     // 32 atoms x 32 threads
            const float* hr = &s_hf[atom * SH];
            float ax = 0.f, ay = 0.f;
#pragma unroll 8
            for (int f = 0; f < 128; ++f) {
                float hv = hr[f];
                float2 wv = ((const float2*)&s_w[f * 64])[cg];
                ax += hv * wv.x; ay += hv * wv.y;
            }
            int c0i = cg * 2;
            float v = silu_f(ax + ob1[c0i + 0]) * ow2[c0i + 0]
                    + silu_f(ay + ob1[c0i + 1]) * ow2[c0i + 1];
            v += __shfl_xor(v, 1, 64);
            v += __shfl_xor(v, 2, 64);
            v += __shfl_xor(v, 4, 64);
            v += __shfl_xor(v, 8, 64);
            v += __shfl_xor(v, 16, 64);
            if ((tid & 31) == 0) atomicAdd(&s_sum, v + ob2[0]);
            __syncthreads();
            if (tid == 0) {
                atomicAdd(&gsum[g], s_sum);
                __threadfence();
                int tk = __hip_atomic_fetch_add(done_cnt, 1, __ATOMIC_ACQ_REL,
                                                __HIP_MEMORY_SCOPE_AGENT);
                s_last = (tk == 4 * GRAPHS - 1);
            }
            __syncthreads();
            if (s_last && tid < GRAPHS) {
                float gg = __hip_atomic_load(&gsum[tid], __ATOMIC_RELAXED,
                                             __HIP_MEMORY_SCOPE_AGENT);
                if (*flag) ((float*)out)[tid] = gg;
                else       ((u16*)out)[tid]   = f2bf(gg);
            }
            break;
        }
    }
}

// ---------------------------------------------------------------------------
extern "C" void kernel_launch(void* const* d_in, const int* in_sizes, int n_in,
                              void* d_out, int out_size, void* d_ws, size_t ws_size,
                              hipStream_t stream) {
    const void* pos  = d_in[0];
    const int*  z    = (const int*)d_in[1];
    // d_in[2] = batch (implicit: graph = i >> 7)
    const void* emb  = d_in[3];
    const void* mw1  = d_in[4];
    const void* mb1  = d_in[5];
    const void* mw2  = d_in[6];
    const void* mb2  = d_in[7];
    const void* l1w  = d_in[8];
    const void* l1b  = d_in[9];
    const void* l2w  = d_in[10];
    const void* l2b  = d_in[11];
    const void* ow1  = d_in[12];
    const void* ob1  = d_in[13];
    const void* ow2  = d_in[14];
    const void* ob2  = d_in[15];

    char* ws = (char*)d_ws;
    const size_t KB = 1024, MB = 1048576;
    int*   w_flag  = (int*)  (ws);
    int*   w_done  = (int*)  (ws + 64);
    int*   w_xfl   = (int*)  (ws + 8 * KB);     // 2048 ints (flags)
    float* c_emb   = (float*)(ws + 112 * KB);
    float* c_mb1   = (float*)(ws + 168 * KB);
    float* c_mb2   = (float*)(ws + 176 * KB);
    float* c_l1b   = (float*)(ws + 184 * KB);
    float* c_l2b   = (float*)(ws + 192 * KB);
    float* c_ow1   = (float*)(ws + 200 * KB);
    float* c_ob1   = (float*)(ws + 236 * KB);
    float* c_ow2   = (float*)(ws + 240 * KB);
    float* c_ob2   = (float*)(ws + 244 * KB);
    float* w_gsum  = (float*)(ws + 248 * KB);
    u16*   c_l1wt  = (u16*)  (ws + 256 * KB);   // 192 KB
    u16*   c_l2wt  = (u16*)  (ws + 448 * KB);   // 192 KB
    int*   rev_cnt = (int*)  (ws + 2  * MB);    // 32 KB
    u32*   w_rev   = (u32*)  (ws + 3  * MB);    // 4 MB (packed)
    u32*   w_pk    = (u32*)  (ws + 21 * MB);    // 6 MB
    u32*   w_xbuf  = (u32*)  (ws + 28 * MB);    // 4 MB (2-deep parity)

    probe_kernel<<<1, 256, 0, stream>>>((const u16*)emb, w_flag, rev_cnt,
                                        w_gsum, w_done, w_xfl);

    IngestDesc dsc;
    const void* srcs[NARR] = {emb, mb1, mb2, l1b, l2b, ow1, ob1, ow2, ob2};
    void* dsts[NARR] = {c_emb, c_mb1, c_mb2, c_l1b, c_l2b, c_ow1, c_ob1,
                        c_ow2, c_ob2};
    int ns_[NARR] = {12800, 768, 768, 768, 768, 8192, 64, 64, 1};
    int total = 0;
    for (int a = 0; a < NARR; ++a) {
        dsc.src[a] = srcs[a]; dsc.dst[a] = dsts[a]; dsc.n[a] = ns_[a];
        total += ns_[a];
    }
    int nb_ing = (total + 255) / 256;
    setup_kernel<<<NB_BUILD + NB_PREP + nb_ing, 256, 0, stream>>>(
        pos, l1w, l2w, c_l1wt, c_l2wt, dsc, total, w_flag, rev_cnt, w_rev);

    vtab_kernel<<<LAYERS * NTAB / 128, 256, 0, stream>>>(
        mw1, mw2, c_mb1, c_mb2, w_flag, w_pk);

    graph_kernel<<<4 * GRAPHS, 1024, 0, stream>>>(
        rev_cnt, w_rev, w_pk, z, c_emb, c_l1wt, c_l1b, c_l2wt, c_l2b,
        c_ow1, c_ob1, c_ow2, c_ob2, w_xbuf, w_xfl,
        w_gsum, w_done, d_out, w_flag);
}

// Round 13
// 227.185 us; speedup vs baseline: 1.0321x; 1.0321x over previous
//
#include <hip/hip_runtime.h>
#include <math.h>

typedef unsigned short u16;
typedef unsigned int   u32;
typedef unsigned long long u64;

#define NATOMS 8192
#define GRAPHS 64
#define KNN    32
#define NGAUSS 50
#define HID    128
#define LAYERS 6
#define NTAB   4096
#define SA     136   // u16 stride, 272B rows (16B-aligned, 4-bank row shift)
#define SW1    72    // u16 stride for staged mw1 rows
#define SH     132   // f32 stride for head h staging

typedef __attribute__((ext_vector_type(8))) short bf16x8;
typedef __attribute__((ext_vector_type(4))) float f32x4;

__device__ __forceinline__ float bf2f(u16 v) {
    return __uint_as_float(((u32)v) << 16);
}
__device__ __forceinline__ u16 f2bf(float f) {
    u32 u = __float_as_uint(f);
    u32 lsb = (u >> 16) & 1u;
    u += 0x7fffu + lsb;
    return (u16)(u >> 16);
}
__device__ __forceinline__ u32 pkbf(float lo, float hi) {
#if __has_builtin(__builtin_amdgcn_cvt_pk_bf16_f32)
    auto r = __builtin_amdgcn_cvt_pk_bf16_f32(lo, hi);
    u32 u; __builtin_memcpy(&u, &r, 4); return u;
#else
    return (u32)f2bf(lo) | ((u32)f2bf(hi) << 16);
#endif
}
__device__ __forceinline__ float silu_f(float x) {
    return x * __builtin_amdgcn_rcpf(1.0f + __expf(-x));
}
__device__ __forceinline__ bf16x8 ldfrag(const u16* p) {
    return *(const bf16x8*)__builtin_assume_aligned(p, 16);
}
__device__ __forceinline__ u64 shfl_xor_u64(u64 v, int mask) {
    u32 lo = (u32)v, hi = (u32)(v >> 32);
    lo = (u32)__shfl_xor((int)lo, mask, 64);
    hi = (u32)__shfl_xor((int)hi, mask, 64);
    return ((u64)hi << 32) | lo;
}
__device__ __forceinline__ float ldf(const void* p, int i, bool f32in) {
    return f32in ? ((const float*)p)[i] : bf2f(((const u16*)p)[i]);
}
union U8 { bf16x8 v; u32 w[4]; };

// ---------------------------------------------------------------------------
// K0: dtype probe + zero rev_cnt/gsum/done/exchange-flags.
// ---------------------------------------------------------------------------
__global__ void probe_kernel(const u16* __restrict__ raw, int* __restrict__ flag,
                             int* __restrict__ rev_cnt, float* __restrict__ gsum,
                             int* __restrict__ done_cnt, int* __restrict__ xflags) {
    __shared__ int s;
    int t = threadIdx.x;
    if (t == 0) s = 0;
    __syncthreads();
    float x = bf2f(raw[2 * t]);
    if (!(fabsf(x) < 1000.0f)) atomicOr(&s, 1);
    for (int i = t; i < NATOMS; i += 256) rev_cnt[i] = 0;
    for (int i = t; i < 2048; i += 256) xflags[i] = 0;
    if (t < GRAPHS) gsum[t] = 0.0f;
    if (t == 0) *done_cnt = 0;
    __syncthreads();
    if (t == 0) *flag = s;
}

// ---------------------------------------------------------------------------
// K1: merged setup — build_graph + weight prep (l1wt/l2wt only) + fp32 ingest.
// rev entries packed: (table_row << 7) | local_sender  (12b + 7b).
// ---------------------------------------------------------------------------
#define NARR 9
struct IngestDesc {
    const void* src[NARR];
    void*       dst[NARR];
    int         n[NARR];
};

#define NB_BUILD 2048
#define NB_PREP  768

__launch_bounds__(256)
__global__ void setup_kernel(const void* __restrict__ pos,
                             const void* __restrict__ l1w, const void* __restrict__ l2w,
                             u16* __restrict__ l1wt, u16* __restrict__ l2wt,
                             IngestDesc d, int total_ing,
                             const int* __restrict__ flag,
                             int* __restrict__ rev_cnt, u32* __restrict__ rev) {
    int bid = blockIdx.x;
    bool f32in = (*flag != 0);
    if (bid < NB_BUILD) {
        int wv = threadIdx.x >> 6, lane = threadIdx.x & 63;
        int t = bid * 4 + wv;
        int tl = t & 127;
        int base = t & ~127;
        float cx = ldf(pos, t * 3 + 0, f32in);
        float cy = ldf(pos, t * 3 + 1, f32in);
        float cz = ldf(pos, t * 3 + 2, f32in);
        u64 key[2];
#pragma unroll
        for (int c = 0; c < 2; ++c) {
            int j = lane + c * 64;
            float jx = ldf(pos, (base + j) * 3 + 0, f32in);
            float jy = ldf(pos, (base + j) * 3 + 1, f32in);
            float jz = ldf(pos, (base + j) * 3 + 2, f32in);
            float dx = __fsub_rn(cx, jx);
            float dy = __fsub_rn(cy, jy);
            float dz = __fsub_rn(cz, jz);
            float d2 = __fadd_rn(__fadd_rn(__fmul_rn(dx, dx), __fmul_rn(dy, dy)),
                                 __fmul_rn(dz, dz));
            bool valid = (j != tl) && (d2 < 100.0f);
            key[c] = valid ? ((((u64)__float_as_uint(d2)) << 32) | (u32)j) : ~0ULL;
        }
#pragma unroll
        for (int k = 2; k <= 128; k <<= 1) {
#pragma unroll
            for (int j = k >> 1; j > 0; j >>= 1) {
                if (j == 64) {
                    u64 lo = key[0] < key[1] ? key[0] : key[1];
                    u64 hi = key[0] < key[1] ? key[1] : key[0];
                    key[0] = lo; key[1] = hi;
                } else {
#pragma unroll
                    for (int r = 0; r < 2; ++r) {
                        u64 o = shfl_xor_u64(key[r], j);
                        u32 ii = (u32)(r * 64 + lane);
                        bool dir = ((ii & (u32)k) == 0);
                        bool lower = ((ii & (u32)j) == 0);
                        bool keep_min = (dir == lower);
                        bool less = key[r] < o;
                        key[r] = (less == keep_min) ? key[r] : o;
                    }
                }
            }
        }
        if (lane < KNN) {
            u64 m = key[0];
            if (m != ~0ULL) {
                float d2 = __uint_as_float((u32)(m >> 32));
                float dd = __fsqrt_rn(d2);
                if (dd < 10.0f) {
                    float u = dd * ((float)(NTAB - 1) / 10.0f);
                    int i0 = (int)(u + 0.5f);          // nearest
                    if (i0 > NTAB - 1) i0 = NTAB - 1;
                    int jn = base + (int)(m & 0xffffffffu);
                    int p = atomicAdd(&rev_cnt[jn], 1);
                    rev[(size_t)jn * 128 + p] = ((u32)i0 << 7) | (u32)(t & 127);
                }
            }
        }
    } else if (bid < NB_BUILD + NB_PREP) {
        int gid = (bid - NB_BUILD) * 256 + threadIdx.x;
        int seg = gid / 98304;
        int tt = gid % 98304;
        int l = tt >> 14;
        int n = (tt >> 7) & 127;
        int k = tt & 127;
        const void* src = (seg == 0) ? l1w : l2w;
        u16* dst = (seg == 0) ? l1wt : l2wt;
        int si = l * 16384 + k * 128 + n;
        float v = f32in ? ((const float*)src)[si] : bf2f(((const u16*)src)[si]);
        dst[tt] = f2bf(v);
    } else {
        int gid = (bid - NB_BUILD - NB_PREP) * 256 + threadIdx.x;
        if (gid < total_ing) {
            int a = 0, off = gid;
            while (off >= d.n[a]) { off -= d.n[a]; ++a; }
            float v = f32in ? ((const float*)d.src[a])[off]
                            : bf2f(((const u16*)d.src[a])[off]);
            ((float*)d.dst[a])[off] = v;
        }
    }
}

// ---------------------------------------------------------------------------
// K4a: filter tables via MFMA. Stages mw1/mw2 straight from the RAW inputs
// with inline transpose + dtype convert.
// ---------------------------------------------------------------------------
__launch_bounds__(256)
__global__ void vtab_kernel(const void* __restrict__ mw1,   // raw [6][50][128]
                            const void* __restrict__ mw2,   // raw [6][128][128]
                            const float* __restrict__ b1,   // [6][128] canonical
                            const float* __restrict__ b2,   // [6][128]
                            const int* __restrict__ flag,
                            u32* __restrict__ pk) {         // [6][NTAB][64]
    __shared__ u16 s_t1[128 * SA];
    __shared__ u16 s_w1[128 * SW1];
    __shared__ u16 s_w2[128 * SA];
    int tid = threadIdx.x;
    int l = blockIdx.x / (NTAB / 128);
    int rbase = (blockIdx.x % (NTAB / 128)) * 128;
    {
        bool f32in = (*flag != 0);
#pragma unroll
        for (int p = 0; p < 32; ++p) {
            int idx = p * 256 + tid;           // 8192 = 128n x 64k
            int k = idx >> 7, n = idx & 127;
            float v = (k < 50) ? ldf(mw1, l * 6400 + k * 128 + n, f32in) : 0.0f;
            s_w1[n * SW1 + k] = f2bf(v);
        }
#pragma unroll
        for (int p = 0; p < 64; ++p) {
            int idx = p * 256 + tid;           // 16384 = 128n x 128k
            int k = idx >> 7, n = idx & 127;
            s_w2[n * SA + k] = f2bf(ldf(mw2, l * 16384 + k * 128 + n, f32in));
        }
    }
    __syncthreads();

    int wv = tid >> 6, lane = tid & 63;
    int quad = lane >> 4, lr = lane & 15;
    int m0 = wv * 32;

    {
        const float wgi = 49.0f / 10.0f;
        const float dstep = 10.0f / (float)(NTAB - 1);
        U8 afr[2][2];
#pragma unroll
        for (int mt = 0; mt < 2; ++mt) {
            float d = (float)(rbase + m0 + mt * 16 + lr) * dstep;
            float u = d * wgi;
#pragma unroll
            for (int kki = 0; kki < 2; ++kki) {
                float t0 = u - (float)(quad * 8) - (float)(kki * 32);
                float vj[8];
#pragma unroll
                for (int j = 0; j < 8; ++j) {
                    float tt = t0 - (float)j;
                    float e = __expf(-0.5f * tt * tt);
                    if (kki == 1 && (quad * 8 + j) >= 18) e = 0.0f;
                    vj[j] = e;
                }
#pragma unroll
                for (int p = 0; p < 4; ++p)
                    afr[mt][kki].w[p] = pkbf(vj[2 * p], vj[2 * p + 1]);
            }
        }
        f32x4 accA[2][8];
#pragma unroll
        for (int mt = 0; mt < 2; ++mt)
#pragma unroll
            for (int nt = 0; nt < 8; ++nt) accA[mt][nt] = (f32x4){0.f, 0.f, 0.f, 0.f};
#pragma unroll
        for (int kki = 0; kki < 2; ++kki) {
#pragma unroll
            for (int nt = 0; nt < 8; ++nt) {
                bf16x8 b = ldfrag(&s_w1[(nt * 16 + lr) * SW1 + kki * 32 + quad * 8]);
                accA[0][nt] = __builtin_amdgcn_mfma_f32_16x16x32_bf16(afr[0][kki].v, b, accA[0][nt], 0, 0, 0);
                accA[1][nt] = __builtin_amdgcn_mfma_f32_16x16x32_bf16(afr[1][kki].v, b, accA[1][nt], 0, 0, 0);
            }
        }
#pragma unroll
        for (int mt = 0; mt < 2; ++mt) {
            int r0 = m0 + mt * 16 + quad * 4;
            u16* tp0 = &s_t1[r0 * SA + lr];
#pragma unroll
            for (int nt = 0; nt < 8; ++nt) {
                int col = nt * 16;
                float bb = b1[l * 128 + col + lr];
                u32 p01 = pkbf(silu_f(accA[mt][nt][0] + bb),
                               silu_f(accA[mt][nt][1] + bb));
                u32 p23 = pkbf(silu_f(accA[mt][nt][2] + bb),
                               silu_f(accA[mt][nt][3] + bb));
                u16* tp = tp0 + col;
                tp[0]      = (u16)p01;
                tp[SA]     = (u16)(p01 >> 16);
                tp[2 * SA] = (u16)p23;
                tp[3 * SA] = (u16)(p23 >> 16);
            }
        }
    }
    // no barrier: Phase B reads only this wave's own 32 t1 rows
    {
        f32x4 accB[2][8];
#pragma unroll
        for (int mt = 0; mt < 2; ++mt)
#pragma unroll
            for (int nt = 0; nt < 8; ++nt) accB[mt][nt] = (f32x4){0.f, 0.f, 0.f, 0.f};
#pragma unroll
        for (int kk = 0; kk < 128; kk += 32) {
            bf16x8 a0 = ldfrag(&s_t1[(m0 + lr)      * SA + kk + quad * 8]);
            bf16x8 a1 = ldfrag(&s_t1[(m0 + 16 + lr) * SA + kk + quad * 8]);
#pragma unroll
            for (int nt = 0; nt < 8; ++nt) {
                bf16x8 b = ldfrag(&s_w2[(nt * 16 + lr) * SA + kk + quad * 8]);
                accB[0][nt] = __builtin_amdgcn_mfma_f32_16x16x32_bf16(a0, b, accB[0][nt], 0, 0, 0);
                accB[1][nt] = __builtin_amdgcn_mfma_f32_16x16x32_bf16(a1, b, accB[1][nt], 0, 0, 0);
            }
        }
        const float dstep = 10.0f / (float)(NTAB - 1);
#pragma unroll
        for (int mt = 0; mt < 2; ++mt) {
            int r0 = m0 + mt * 16 + quad * 4;
            float cv[4];
#pragma unroll
            for (int r = 0; r < 4; ++r) {
                float d = (float)(rbase + r0 + r) * dstep;
                cv[r] = 0.5f * (cosf(d * 3.14159265f / 10.0f) + 1.0f);
            }
#pragma unroll
            for (int nt = 0; nt < 8; ++nt) {
                int col = nt * 16 + lr;
                float bb = b2[l * 128 + col];
#pragma unroll
                for (int r = 0; r < 4; ++r) {
                    float val = (accB[mt][nt][r] + bb) * cv[r];
                    float oth = __shfl_xor(val, 1, 64);
                    if ((lr & 1) == 0) {
                        int row = rbase + r0 + r;
                        pk[((size_t)l * NTAB + row) * 64 + (col >> 1)] =
                            pkbf(val, oth);
                    }
                }
            }
        }
    }
}

// ---------------------------------------------------------------------------
// K5: graph kernel — FOUR BLOCKS PER GRAPH (256 blocks x 1024 thr = all CUs).
// r13 = r11 verbatim (best measured: graph 99.2us, total 229.6us). r12's
// wave-partitioned pipelined pull REVERTED: 16 per-wave system-scope spinners
// + strided pulls raised IC traffic (FETCH 19.1->21.8MB, WRITE 23.6->29.8MB)
// and cost 3us. The r11 exchange (3 spinners, barrier, single coalesced pull)
// is the measured optimum of this protocol family (r7/r10/r12 all lost).
// Block-level serpentine degree balance + wave-level w/31-w pairing retained.
// ---------------------------------------------------------------------------
#define AGG_ISSUE(T, X, base, ev)                                              \
    {                                                                          \
        _Pragma("unroll") for (int q = 0; q < 8; ++q) {                        \
            int e = (base) + q;                                                \
            u32 pe = __builtin_amdgcn_readlane((ev), e & 63);                  \
            int sy = (int)(pe >> 7);                                           \
            int sx = (int)(pe & 127u);                                         \
            T[q] = pkl[(size_t)sy * 64 + lane];                                \
            X[q] = *(const u32*)&s_x[sx * SA + c2];                            \
        }                                                                      \
    }

#define AGG_COMPUTE(T, X)                                                      \
    {                                                                          \
        _Pragma("unroll") for (int q = 0; q < 8; ++q) {                        \
            float v0 = bf2f((u16)T[q]) * bf2f((u16)X[q]);                      \
            float v1 = bf2f((u16)(T[q] >> 16)) * bf2f((u16)(X[q] >> 16));      \
            switch (q & 3) {                                                   \
                case 0: a0 += v0; a1 += v1; break;                             \
                case 1: b0 += v0; b1v += v1; break;                            \
                case 2: c0 += v0; c1 += v1; break;                             \
                default: d0 += v0; d1 += v1; break;                            \
            }                                                                  \
        }                                                                      \
    }

__launch_bounds__(1024, 1)
__global__ void graph_kernel(const int* __restrict__ rev_cnt,
                             const u32* __restrict__ rev,
                             const u32* __restrict__ pk,      // [6][NTAB][64]
                             const int* __restrict__ z,
                             const float* __restrict__ emb,
                             const u16* __restrict__ l1wt,
                             const float* __restrict__ l1b,
                             const u16* __restrict__ l2wt,
                             const float* __restrict__ l2b,
                             const float* __restrict__ ow1,
                             const float* __restrict__ ob1,
                             const float* __restrict__ ow2,
                             const float* __restrict__ ob2,
                             u32* __restrict__ xbuf,          // [256][2][2048]
                             int* __restrict__ xflags,        // [64][4][8]
                             float* __restrict__ gsum,
                             int* __restrict__ done_cnt,
                             void* __restrict__ out,
                             const int* __restrict__ flag) {
    __shared__ __align__(16) u16 s_x[128 * SA];      // full xj (head: ow1 f32)
    __shared__ __align__(16) u16 s_hb[64 * SA];      // own h bf16 (32 used; pad)
    __shared__ __align__(16) u16 s_pair[2 * 64 * SA];// agg hi|lo (head: h f32)
    __shared__ float s_b1a[LAYERS * 128];            // all-layer biases
    __shared__ float s_b2a[LAYERS * 128];
    __shared__ int s_gp[4][32];                      // serpentine loc->glob row
    __shared__ float s_sum;
    __shared__ int s_last;

    u16* s_ahi = s_pair;
    u16* s_alo = s_pair + 64 * SA;

    int tid = threadIdx.x;
    int bid = blockIdx.x;
    int g = bid & 63, q4 = bid >> 6;        // quarter 0..3
    int abase = g * 128;
    int w = tid >> 6, lane = tid & 63;
    int quad = lane >> 4, lr = lane & 15;
    int rowt = (w >> 3) * 16;               // compact row tile (0 or 16)
    int coln = (w & 7) * 16;                // col tile base (0..112)
    int c2 = lane * 2;

    float hreg[4];                          // h[rowt+quad*4+r][coln+lr] compact

    // ---- hoisted: all-layer biases -> LDS (written once, covered by sync)
    for (int i = tid; i < LAYERS * 128; i += 1024) {
        s_b1a[i] = l1b[i];
        s_b2a[i] = l2b[i];
    }

    // ---- wave 0: sort ALL 128 receiver degrees desc (2 keys/lane bitonic,
    //      deterministic & identical in all 4 partner blocks), then assign
    //      serpentine: position p -> round r=p>>2, col c=p&3, block
    //      q=(r&1)?3-c:c. Block totals equalize.
    if (w == 0) {
        u32 key[2];
#pragma unroll
        for (int c = 0; c < 2; ++c) {
            int rowi = lane + c * 64;
            int dg = rev_cnt[abase + rowi];
            key[c] = ((u32)dg << 8) | (u32)rowi;
        }
#pragma unroll
        for (int k = 2; k <= 128; k <<= 1) {
#pragma unroll
            for (int j = k >> 1; j > 0; j >>= 1) {
                if (j == 64) {
                    u32 mx = key[0] > key[1] ? key[0] : key[1];
                    u32 mn = key[0] > key[1] ? key[1] : key[0];
                    key[0] = mx; key[1] = mn;
                } else {
#pragma unroll
                    for (int r = 0; r < 2; ++r) {
                        u32 o = (u32)__shfl_xor((int)key[r], j, 64);
                        u32 ii = (u32)(r * 64 + lane);
                        bool dir = ((ii & (u32)k) == 0);
                        bool lower = ((ii & (u32)j) == 0);
                        bool keep_max = (dir == lower);
                        bool greater = key[r] > o;
                        key[r] = (greater == keep_max) ? key[r] : o;
                    }
                }
            }
        }
#pragma unroll
        for (int c = 0; c < 2; ++c) {
            int p = lane + c * 64;
            int r = p >> 2, cc = p & 3;
            int q = (r & 1) ? (3 - cc) : cc;
            s_gp[q][r] = (int)(key[c] & 0xffu);
        }
    }
    __syncthreads();

    // ---- init: stage own 32 emb[z] rows (compact order) -> s_hb (bf16)
    {
        int r = tid >> 5, cb = (tid & 31) * 4;
        const float* src = emb + (size_t)z[abase + s_gp[q4][r]] * 128 + cb;
        float4 v = *(const float4*)src;
        u32* dd = (u32*)&s_hb[r * SA + cb];
        dd[0] = pkbf(v.x, v.y); dd[1] = pkbf(v.z, v.w);
    }

    // ---- hoisted: per-wave receiver descriptors (layer-invariant, balanced)
    int rloc[2];
    rloc[0] = w;
    rloc[1] = 31 - w;
    int grow[2];
    grow[0] = s_gp[q4][rloc[0]];
    grow[1] = s_gp[q4][rloc[1]];
    int dgv[2];
    u32 eAv[2], eBv[2];
#pragma unroll
    for (int rr = 0; rr < 2; ++rr) {
        int j = abase + grow[rr];
        dgv[rr] = rev_cnt[j];
        eAv[rr] = rev[(size_t)j * 128 + lane];
        eBv[rr] = (dgv[rr] > 64) ? rev[(size_t)j * 128 + 64 + lane] : eAv[rr];
    }
    __syncthreads();

    // ---- gemm0: own xj(0) rows -> s_x[glob rows]
    {
        f32x4 acc = (f32x4){0.f, 0.f, 0.f, 0.f};
#pragma unroll
        for (int kk = 0; kk < 128; kk += 32) {
            bf16x8 a = ldfrag(&s_hb[(rowt + lr) * SA + kk + quad * 8]);
            bf16x8 b = ldfrag(l1wt + (coln + lr) * 128 + kk + quad * 8);
            acc = __builtin_amdgcn_mfma_f32_16x16x32_bf16(a, b, acc, 0, 0, 0);
        }
#pragma unroll
        for (int r = 0; r < 4; ++r) {
            int col = coln + lr;
            s_x[s_gp[q4][rowt + quad * 4 + r] * SA + col] =
                f2bf(acc[r] + s_b1a[col]);
        }
    }

    for (int l = 0; l <= LAYERS; ++l) {
        if (l < LAYERS) {
            // ---- all-gather exchange e=l: own quarter out, 3 partners in
            int e = l;
            u64* xbw = (u64*)(xbuf + ((size_t)bid * 2 + (e & 1)) * 2048);
            __syncthreads();                    // s_x own writes visible
            {
                // 1024 u64 = 32 loc-rows x 32 (u64 covers 4 u16)
                u64 v = *(const u64*)&s_x[s_gp[q4][tid >> 5] * SA +
                                          (tid & 31) * 4];
                __hip_atomic_store(&xbw[tid], v, __ATOMIC_RELAXED,
                                   __HIP_MEMORY_SCOPE_SYSTEM);
            }
            __syncthreads();                    // vmcnt drained: data at IC
            if (tid == 0)
                __hip_atomic_store(&xflags[(g * 4 + q4) * 8 + e], 1,
                                   __ATOMIC_RELAXED, __HIP_MEMORY_SCOPE_SYSTEM);
            if (tid < 3) {
                int pq = (q4 + 1 + tid) & 3;
                const int* pf = &xflags[(g * 4 + pq) * 8 + e];
                while (__hip_atomic_load(pf, __ATOMIC_RELAXED,
                                         __HIP_MEMORY_SCOPE_SYSTEM) == 0)
                    __builtin_amdgcn_s_sleep(1);
            }
            __syncthreads();
#pragma unroll
            for (int k = 0; k < 3; ++k) {
                int pq = (q4 + 1 + k) & 3;
                const u64* xbr = (const u64*)(xbuf +
                    ((size_t)(g + 64 * pq) * 2 + (e & 1)) * 2048);
                u64 v = __hip_atomic_load(&xbr[tid], __ATOMIC_RELAXED,
                                          __HIP_MEMORY_SCOPE_SYSTEM);
                *(u64*)&s_x[s_gp[pq][tid >> 5] * SA + (tid & 31) * 4] = v;
            }
            __syncthreads();
        }
        if (l == LAYERS) break;

        const u32* pkl = pk + (size_t)l * NTAB * 64;

        // ---- Phase 1: agg — wave w owns compact receivers {w, 31-w}
#pragma unroll
        for (int rr = 0; rr < 2; ++rr) {
            int row = rloc[rr];                     // compact 0..31
            int deg = dgv[rr];
            u32 e0 = eAv[rr];
            u32 e1 = eBv[rr];
            float a0 = 0.f, a1 = 0.f, b0 = 0.f, b1v = 0.f;
            float c0 = 0.f, c1 = 0.f, d0 = 0.f, d1 = 0.f;
            u32 tA[8], xA[8], tB[8], xB[8];
            int ng = deg >> 3;
            if (ng > 0) {
                AGG_ISSUE(tA, xA, 0, e0);
                int gi = 1;
                for (; gi + 1 < ng; gi += 2) {
                    u32 evB = (gi < 8) ? e0 : e1;
                    AGG_ISSUE(tB, xB, gi * 8, evB);
                    AGG_COMPUTE(tA, xA);
                    u32 evA = ((gi + 1) < 8) ? e0 : e1;
                    AGG_ISSUE(tA, xA, (gi + 1) * 8, evA);
                    AGG_COMPUTE(tB, xB);
                }
                if (gi < ng) {
                    u32 evB = (gi < 8) ? e0 : e1;
                    AGG_ISSUE(tB, xB, gi * 8, evB);
                    AGG_COMPUTE(tA, xA);
                    AGG_COMPUTE(tB, xB);
                } else {
                    AGG_COMPUTE(tA, xA);
                }
            }
            for (int it = ng * 8; it < deg; ++it) {
                u32 ev = (it < 64) ? e0 : e1;
                u32 pe = __builtin_amdgcn_readlane(ev, it & 63);
                int sy = (int)(pe >> 7);
                int sx = (int)(pe & 127u);
                u32 t = pkl[(size_t)sy * 64 + lane];
                u32 x = *(const u32*)&s_x[sx * SA + c2];
                a0 += bf2f((u16)t) * bf2f((u16)x);
                a1 += bf2f((u16)(t >> 16)) * bf2f((u16)(x >> 16));
            }
            float sxv = (a0 + b0) + (c0 + d0);
            float syv = (a1 + b1v) + (c1 + d1);
            u32 hp = pkbf(sxv, syv);
            u32 lp = pkbf(sxv - bf2f((u16)hp), syv - bf2f((u16)(hp >> 16)));
            *(u32*)&s_ahi[row * SA + c2] = hp;
            *(u32*)&s_alo[row * SA + c2] = lp;
        }
        __syncthreads();

        // ---- Phase 2: h += silu(agg @ l2w + b2) [hi/lo A], h in VGPRs
        {
            const u16* B2t = l2wt + (size_t)l * 16384;
            f32x4 acc = (f32x4){0.f, 0.f, 0.f, 0.f};
#pragma unroll
            for (int kk = 0; kk < 128; kk += 32) {
                bf16x8 ah = ldfrag(&s_ahi[(rowt + lr) * SA + kk + quad * 8]);
                bf16x8 al = ldfrag(&s_alo[(rowt + lr) * SA + kk + quad * 8]);
                bf16x8 b = ldfrag(B2t + (coln + lr) * 128 + kk + quad * 8);
                acc = __builtin_amdgcn_mfma_f32_16x16x32_bf16(ah, b, acc, 0, 0, 0);
                acc = __builtin_amdgcn_mfma_f32_16x16x32_bf16(al, b, acc, 0, 0, 0);
            }
            if (l == LAYERS - 1 && tid == 0) s_sum = 0.0f;
            int col = coln + lr;
#pragma unroll
            for (int r = 0; r < 4; ++r) {
                int row = rowt + quad * 4 + r;          // compact
                float hold = (l == 0)
                    ? emb[(size_t)z[abase + s_gp[q4][row]] * 128 + col]
                    : hreg[r];
                float hn = hold + silu_f(acc[r] + s_b2a[l * 128 + col]);
                hreg[r] = hn;
                if (l < LAYERS - 1) s_hb[row * SA + col] = f2bf(hn);
            }
        }
        __syncthreads();

        if (l < LAYERS - 1) {
            // ---- Phase 3: own xj(l+1) rows -> s_x[glob rows]
            const u16* B1n = l1wt + (size_t)(l + 1) * 16384;
            f32x4 ac2 = (f32x4){0.f, 0.f, 0.f, 0.f};
#pragma unroll
            for (int kk = 0; kk < 128; kk += 32) {
                bf16x8 a = ldfrag(&s_hb[(rowt + lr) * SA + kk + quad * 8]);
                bf16x8 b = ldfrag(B1n + (coln + lr) * 128 + kk + quad * 8);
                ac2 = __builtin_amdgcn_mfma_f32_16x16x32_bf16(a, b, ac2, 0, 0, 0);
            }
            int col = coln + lr;
#pragma unroll
            for (int r = 0; r < 4; ++r) {
                s_x[s_gp[q4][rowt + quad * 4 + r] * SA + col] =
                    f2bf(ac2[r] + s_b1a[(l + 1) * 128 + col]);
            }
            // exchange at top of next iteration (e = l+1)
        } else {
            // ---- Last layer: head on own 32 atoms (compact) from hreg
            float* s_hf = (float*)s_pair;       // 32*SH*4 = 16.9KB
            float* s_w  = (float*)s_x;          // 32KB (ow1 [128][64])
            {
                float4* dst = (float4*)s_w;
                const float4* src4 = (const float4*)ow1;
                dst[tid] = src4[tid];
                dst[tid + 1024] = src4[tid + 1024];
            }
#pragma unroll
            for (int r = 0; r < 4; ++r)
                s_hf[(rowt + quad * 4 + r) * SH + coln + lr] = hreg[r];
            __syncthreads();
            int atom = tid >> 5, cg = tid & 31;     // 32 atoms x 32 threads
            const float* hr = &s_hf[atom * SH];
            float ax = 0.f, ay = 0.f;
#pragma unroll 8
            for (int f = 0; f < 128; ++f) {
                float hv = hr[f];
                float2 wv = ((const float2*)&s_w[f * 64])[cg];
                ax += hv * wv.x; ay += hv * wv.y;
            }
            int c0i = cg * 2;
            float v = silu_f(ax + ob1[c0i + 0]) * ow2[c0i + 0]
                    + silu_f(ay + ob1[c0i + 1]) * ow2[c0i + 1];
            v += __shfl_xor(v, 1, 64);
            v += __shfl_xor(v, 2, 64);
            v += __shfl_xor(v, 4, 64);
            v += __shfl_xor(v, 8, 64);
            v += __shfl_xor(v, 16, 64);
            if ((tid & 31) == 0) atomicAdd(&s_sum, v + ob2[0]);
            __syncthreads();
            if (tid == 0) {
                atomicAdd(&gsum[g], s_sum);
                __threadfence();
                int tk = __hip_atomic_fetch_add(done_cnt, 1, __ATOMIC_ACQ_REL,
                                                __HIP_MEMORY_SCOPE_AGENT);
                s_last = (tk == 4 * GRAPHS - 1);
            }
            __syncthreads();
            if (s_last && tid < GRAPHS) {
                float gg = __hip_atomic_load(&gsum[tid], __ATOMIC_RELAXED,
                                             __HIP_MEMORY_SCOPE_AGENT);
                if (*flag) ((float*)out)[tid] = gg;
                else       ((u16*)out)[tid]   = f2bf(gg);
            }
            break;
        }
    }
}

// ---------------------------------------------------------------------------
extern "C" void kernel_launch(void* const* d_in, const int* in_sizes, int n_in,
                              void* d_out, int out_size, void* d_ws, size_t ws_size,
                              hipStream_t stream) {
    const void* pos  = d_in[0];
    const int*  z    = (const int*)d_in[1];
    // d_in[2] = batch (implicit: graph = i >> 7)
    const void* emb  = d_in[3];
    const void* mw1  = d_in[4];
    const void* mb1  = d_in[5];
    const void* mw2  = d_in[6];
    const void* mb2  = d_in[7];
    const void* l1w  = d_in[8];
    const void* l1b  = d_in[9];
    const void* l2w  = d_in[10];
    const void* l2b  = d_in[11];
    const void* ow1  = d_in[12];
    const void* ob1  = d_in[13];
    const void* ow2  = d_in[14];
    const void* ob2  = d_in[15];

    char* ws = (char*)d_ws;
    const size_t KB = 1024, MB = 1048576;
    int*   w_flag  = (int*)  (ws);
    int*   w_done  = (int*)  (ws + 64);
    int*   w_xfl   = (int*)  (ws + 8 * KB);     // 2048 ints (flags)
    float* c_emb   = (float*)(ws + 112 * KB);
    float* c_mb1   = (float*)(ws + 168 * KB);
    float* c_mb2   = (float*)(ws + 176 * KB);
    float* c_l1b   = (float*)(ws + 184 * KB);
    float* c_l2b   = (float*)(ws + 192 * KB);
    float* c_ow1   = (float*)(ws + 200 * KB);
    float* c_ob1   = (float*)(ws + 236 * KB);
    float* c_ow2   = (float*)(ws + 240 * KB);
    float* c_ob2   = (float*)(ws + 244 * KB);
    float* w_gsum  = (float*)(ws + 248 * KB);
    u16*   c_l1wt  = (u16*)  (ws + 256 * KB);   // 192 KB
    u16*   c_l2wt  = (u16*)  (ws + 448 * KB);   // 192 KB
    int*   rev_cnt = (int*)  (ws + 2  * MB);    // 32 KB
    u32*   w_rev   = (u32*)  (ws + 3  * MB);    // 4 MB (packed)
    u32*   w_pk    = (u32*)  (ws + 21 * MB);    // 6 MB
    u32*   w_xbuf  = (u32*)  (ws + 28 * MB);    // 4 MB (2-deep parity)

    probe_kernel<<<1, 256, 0, stream>>>((const u16*)emb, w_flag, rev_cnt,
                                        w_gsum, w_done, w_xfl);

    IngestDesc dsc;
    const void* srcs[NARR] = {emb, mb1, mb2, l1b, l2b, ow1, ob1, ow2, ob2};
    void* dsts[NARR] = {c_emb, c_mb1, c_mb2, c_l1b, c_l2b, c_ow1, c_ob1,
                        c_ow2, c_ob2};
    int ns_[NARR] = {12800, 768, 768, 768, 768, 8192, 64, 64, 1};
    int total = 0;
    for (int a = 0; a < NARR; ++a) {
        dsc.src[a] = srcs[a]; dsc.dst[a] = dsts[a]; dsc.n[a] = ns_[a];
        total += ns_[a];
    }
    int nb_ing = (total + 255) / 256;
    setup_kernel<<<NB_BUILD + NB_PREP + nb_ing, 256, 0, stream>>>(
        pos, l1w, l2w, c_l1wt, c_l2wt, dsc, total, w_flag, rev_cnt, w_rev);

    vtab_kernel<<<LAYERS * NTAB / 128, 256, 0, stream>>>(
        mw1, mw2, c_mb1, c_mb2, w_flag, w_pk);

    graph_kernel<<<4 * GRAPHS, 1024, 0, stream>>>(
        rev_cnt, w_rev, w_pk, z, c_emb, c_l1wt, c_l1b, c_l2wt, c_l2b,
        c_ow1, c_ob1, c_ow2, c_ob2, w_xbuf, w_xfl,
        w_gsum, w_done, d_out, w_flag);
}